// Round 13
// baseline (562.246 us; speedup 1.0000x reference)
//
#include <hip/hip_runtime.h>
#include <stdint.h>

// Problem constants
#define kB  16384
#define kD  1024
#define kDE 512

typedef __bf16 bf16x8 __attribute__((ext_vector_type(8)));
typedef float  f32x4  __attribute__((ext_vector_type(4)));

__device__ __forceinline__ unsigned short f2bf(float f) {
    union { float f; unsigned u; } v; v.f = f;
    unsigned r = v.u + 0x7FFFu + ((v.u >> 16) & 1u);   // round-to-nearest-even
    return (unsigned short)(r >> 16);
}

__device__ __forceinline__ void async16(unsigned short* lds, const unsigned short* g) {
    __builtin_amdgcn_global_load_lds(
        (const __attribute__((address_space(1))) unsigned int*)g,
        (__attribute__((address_space(3))) unsigned int*)lds, 16, 0, 0);
}

// ---------------- prep: transpose + convert weights to bf16 ----------------
__global__ __launch_bounds__(256) void prep_w(const float* __restrict__ Wsh,
                                              const float* __restrict__ Wsp,
                                              unsigned short* __restrict__ Wt) {
    __shared__ float tile[64][65];
    const int slot = blockIdx.z;
    const int k0 = blockIdx.x * 64;
    const int n0 = blockIdx.y * 64;
    const float* src = (slot < 4) ? (Wsh + (size_t)slot * kD * kDE)
                                  : (Wsp + (size_t)(slot - 4) * kD * kDE);
    const int tid = threadIdx.x;
    const int lr = tid >> 4, lc = (tid & 15) * 4;
#pragma unroll
    for (int i = 0; i < 4; i++) {
        const float4 v = *(const float4*)&src[(size_t)(k0 + lr + i * 16) * kDE + n0 + lc];
        tile[lr + i * 16][lc + 0] = v.x;
        tile[lr + i * 16][lc + 1] = v.y;
        tile[lr + i * 16][lc + 2] = v.z;
        tile[lr + i * 16][lc + 3] = v.w;
    }
    __syncthreads();
    const int wn = tid >> 2, wk = (tid & 3) * 16;
    unsigned short* dst = Wt + (size_t)slot * kDE * kD + (size_t)(n0 + wn) * kD + k0 + wk;
#pragma unroll
    for (int j = 0; j < 4; j++) {
        ushort4 h;
        h.x = f2bf(tile[wk + j * 4 + 0][wn]);
        h.y = f2bf(tile[wk + j * 4 + 1][wn]);
        h.z = f2bf(tile[wk + j * 4 + 2][wn]);
        h.w = f2bf(tile[wk + j * 4 + 3][wn]);
        *(ushort4*)(dst + j * 4) = h;
    }
}

// ------------- fused x fp32->bf16 conversion + gate softmax ---------------
__global__ __launch_bounds__(256) void conv_gate(
    const float* __restrict__ x0, const float* __restrict__ x1,
    const float* __restrict__ Wg, const float* __restrict__ bg,
    unsigned short* __restrict__ xb, float* __restrict__ g) {
    const int wid = threadIdx.x >> 6, lane = threadIdx.x & 63;
    const int r = blockIdx.x * 4 + wid;
    const int t = r >> 14, b = r & 16383;
    const float* xrow = (t ? x1 : x0) + (size_t)b * kD;
    unsigned short* xbrow = xb + (size_t)(t * kB + b) * kD;
    const float* Wgt = Wg + t * kD * 8;
    float p[8] = {0.f,0.f,0.f,0.f,0.f,0.f,0.f,0.f};
#pragma unroll
    for (int it = 0; it < 4; it++) {
        const int d0 = it * 256 + lane * 4;
        const float4 v = *(const float4*)(xrow + d0);
        ushort4 h;
        h.x = f2bf(v.x); h.y = f2bf(v.y); h.z = f2bf(v.z); h.w = f2bf(v.w);
        *(ushort4*)(xbrow + d0) = h;
        const float xv[4] = {v.x, v.y, v.z, v.w};
#pragma unroll
        for (int j = 0; j < 4; j++) {
            const float* wrow = Wgt + (size_t)(d0 + j) * 8;
            const float4 wa = *(const float4*)wrow;
            const float4 wb = *(const float4*)(wrow + 4);
            p[0] += xv[j] * wa.x; p[1] += xv[j] * wa.y;
            p[2] += xv[j] * wa.z; p[3] += xv[j] * wa.w;
            p[4] += xv[j] * wb.x; p[5] += xv[j] * wb.y;
            p[6] += xv[j] * wb.z; p[7] += xv[j] * wb.w;
        }
    }
#pragma unroll
    for (int e = 0; e < 8; e++) {
        float v = p[e];
#pragma unroll
        for (int s = 1; s < 64; s <<= 1) v += __shfl_xor(v, s, 64);
        p[e] = v;
    }
    float lg[8];
#pragma unroll
    for (int e = 0; e < 8; e++) lg[e] = p[e] + bg[t * 8 + e];
    float mx = lg[0];
#pragma unroll
    for (int e = 1; e < 8; e++) mx = fmaxf(mx, lg[e]);
    float s = 0.f;
#pragma unroll
    for (int e = 0; e < 8; e++) { lg[e] = __expf(lg[e] - mx); s += lg[e]; }
    const float inv = 1.f / s;
    if (lane == 0) {
        float* gp = g + (size_t)(t * kB + b) * 8;
        float4 g0 = {lg[0]*inv, lg[1]*inv, lg[2]*inv, lg[3]*inv};
        float4 g1 = {lg[4]*inv, lg[5]*inv, lg[6]*inv, lg[7]*inv};
        *(float4*)gp = g0;
        *(float4*)(gp + 4) = g1;
    }
}

// ------------ fused MoE GEMM: producer/consumer wave specialization --------
// 640 threads = 8 consumer waves (R6's exact compute: 128 rows x 8e x 64
// cols, BK=64, dbuf) + 2 producer waves owning ALL global_load_lds staging.
// Consumers' loop body = pure {24 ds_read + 64 MFMA}: no VMEM issue, no
// vmcnt stall. Producers issue 40 loads/step each, then absorb the vmcnt(0)
// drain while consumers compute (~2500 cyc cover >> 900 cyc HBM latency).
// ONE barrier per K-step (audit: tile-k ready <= producer vmcnt(0) before
// barrier; buf overwrite safe <= reads retired before preceding barrier).
// sched_barrier(0) pins memory ops inside their windows (R9 lesson).
__global__ __launch_bounds__(640, 1) void moe_gemm(
    const unsigned short* __restrict__ xb, const unsigned short* __restrict__ Wt,
    const float* __restrict__ g, const float* __restrict__ bsh,
    const float* __restrict__ bsp, float* __restrict__ out) {
    __shared__ __align__(16) unsigned short As[2][128 * 64];      // 32 KB
    __shared__ __align__(16) unsigned short Bs[2][8 * 64 * 64];   // 128 KB

    // XCD-bijective swizzle (nwg=2048, %8==0) — R6's proven mapping
    const int bid = blockIdx.x;
    const int swz = (bid & 7) * 256 + (bid >> 3);
    const int ct = swz & 7;
    const int rt = (swz >> 3) & 127;
    const int t  = swz >> 10;
    const int n0 = ct * 64;

    const int tid = threadIdx.x, wid = tid >> 6, lane = tid & 63;
    const bool consumer = (wid < 8);
    const int wr = (wid >> 2) & 1, wc = wid & 3;

    const int swzChunk = ((lane & 7) ^ ((lane >> 3) & 7)) * 8;

    // ---- producer addressing: waves 8,9 each replicate 4 consumer-wave
    //      address sets (identical src/dest math to R6's staging) ----
    const int p4 = consumer ? 0 : (wid - 8) * 4;
    const unsigned short* aP[4];
    const unsigned short* bP[4];
#pragma unroll
    for (int jj = 0; jj < 4; jj++) {
        const int w = p4 + jj;
        aP[jj] = xb + (size_t)t * kB * kD +
                 (size_t)(rt * 128 + w * 16 + (lane >> 3)) * kD + swzChunk;
        const int slotW = (w < 4) ? w : (4 + t * 4 + (w - 4));
        bP[jj] = Wt + (size_t)slotW * kDE * kD +
                 (size_t)(n0 + (lane >> 3)) * kD + swzChunk;
    }

    // ---- consumer fragment read offsets (R6-verified) ----
    const int rAbase = (wr * 64 + (lane & 15)) * 64;
    const int bOff   = (wc * 16 + (lane & 15)) * 64;
    const int lx     = lane & 7;
    const int kg     = lane >> 4;

    f32x4 acc[8][4];
#pragma unroll
    for (int e = 0; e < 8; e++)
#pragma unroll
        for (int m = 0; m < 4; m++) acc[e][m] = (f32x4){0.f, 0.f, 0.f, 0.f};

#define P_STAGE(buf, ktn)                                                     \
    {                                                                         \
        _Pragma("unroll")                                                     \
        for (int jj = 0; jj < 4; jj++) {                                      \
            async16(&As[buf][(p4 + jj) * 1024], aP[jj] + (ktn) * 64);         \
            async16(&As[buf][(p4 + jj) * 1024 + 512],                         \
                    aP[jj] + (ktn) * 64 + 8 * kD);                            \
            _Pragma("unroll")                                                 \
            for (int j = 0; j < 8; j++)                                       \
                async16(&Bs[buf][(p4 + jj) * 4096 + j * 512],                 \
                        bP[jj] + (ktn) * 64 + j * 8 * kD);                    \
        }                                                                     \
        asm volatile("s_waitcnt vmcnt(0)" ::: "memory");                      \
    }

#define C_COMPUTE(buf)                                                        \
    {                                                                         \
        _Pragma("unroll")                                                     \
        for (int ks = 0; ks < 2; ks++) {                                      \
            const int p8 = ((ks * 4 + kg) ^ lx) * 8;                          \
            bf16x8 af[4];                                                     \
            _Pragma("unroll")                                                 \
            for (int m = 0; m < 4; m++)                                       \
                af[m] = *(const bf16x8*)&As[buf][rAbase + m * 1024 + p8];     \
            _Pragma("unroll")                                                 \
            for (int e = 0; e < 8; e++) {                                     \
                bf16x8 bf = *(const bf16x8*)&Bs[buf][e * 4096 + bOff + p8];   \
                _Pragma("unroll")                                             \
                for (int m = 0; m < 4; m++)                                   \
                    acc[e][m] = __builtin_amdgcn_mfma_f32_16x16x32_bf16(      \
                        af[m], bf, acc[e][m], 0, 0, 0);                       \
            }                                                                 \
        }                                                                     \
    }

    // prologue: producers stage tile 0 into buf 0 and drain it
    if (!consumer) P_STAGE(0, 0);

    for (int kt2 = 0; kt2 < 8; ++kt2) {
        // --- step A: compute tile 2k (buf0); stage tile 2k+1 -> buf1 ---
        __builtin_amdgcn_s_barrier();
        __builtin_amdgcn_sched_barrier(0);
        if (consumer) { C_COMPUTE(0); }
        else          { P_STAGE(1, kt2 * 2 + 1); }
        __builtin_amdgcn_sched_barrier(0);
        // --- step B: compute tile 2k+1 (buf1); stage tile 2k+2 -> buf0 ---
        __builtin_amdgcn_s_barrier();
        __builtin_amdgcn_sched_barrier(0);
        if (consumer) { C_COMPUTE(1); }
        else          { P_STAGE(0, (kt2 * 2 + 2) & 15); }   // tail wrap benign
        __builtin_amdgcn_sched_barrier(0);
    }

#undef P_STAGE
#undef C_COMPUTE

    if (!consumer) return;

    // ---- epilogue: out = sum_e g_e * relu(acc[e] + bias_e) ----
    const int col = n0 + wc * 16 + (lane & 15);
    float bv[8];
#pragma unroll
    for (int e = 0; e < 8; e++)
        bv[e] = (e < 4) ? bsh[e * kDE + col] : bsp[(t * 4 + (e - 4)) * kDE + col];

#pragma unroll
    for (int m = 0; m < 4; m++) {
        const int r0 = rt * 128 + wr * 64 + m * 16 + kg * 4;
#pragma unroll
        for (int q = 0; q < 4; q++) {
            const float* gp = g + ((size_t)t * kB + r0 + q) * 8;
            const float4 ga = *(const float4*)gp;
            const float4 gb = *(const float4*)(gp + 4);
            float s = ga.x * fmaxf(acc[0][m][q] + bv[0], 0.f)
                    + ga.y * fmaxf(acc[1][m][q] + bv[1], 0.f)
                    + ga.z * fmaxf(acc[2][m][q] + bv[2], 0.f)
                    + ga.w * fmaxf(acc[3][m][q] + bv[3], 0.f)
                    + gb.x * fmaxf(acc[4][m][q] + bv[4], 0.f)
                    + gb.y * fmaxf(acc[5][m][q] + bv[5], 0.f)
                    + gb.z * fmaxf(acc[6][m][q] + bv[6], 0.f)
                    + gb.w * fmaxf(acc[7][m][q] + bv[7], 0.f);
            out[((size_t)(r0 + q) * 2 + t) * kDE + col] = s;
        }
    }
}

extern "C" void kernel_launch(void* const* d_in, const int* in_sizes, int n_in,
                              void* d_out, int out_size, void* d_ws, size_t ws_size,
                              hipStream_t stream) {
    const float* x0  = (const float*)d_in[0];
    const float* x1  = (const float*)d_in[1];
    const float* Wsh = (const float*)d_in[2];
    const float* bsh = (const float*)d_in[3];
    const float* Wsp = (const float*)d_in[4];
    const float* bsp = (const float*)d_in[5];
    const float* Wg  = (const float*)d_in[6];
    const float* bg  = (const float*)d_in[7];
    float* out = (float*)d_out;

    // ws layout (bytes): xb 67108864 | Wt 12582912 | g 1048576
    char* ws = (char*)d_ws;
    unsigned short* xb = (unsigned short*)ws;
    unsigned short* Wt = (unsigned short*)(ws + 67108864);
    float* g  = (float*)(ws + 67108864 + 12582912);

    prep_w<<<dim3(16, 8, 12), dim3(256), 0, stream>>>(Wsh, Wsp, Wt);
    conv_gate<<<dim3(8192), dim3(256), 0, stream>>>(x0, x1, Wg, bg, xb, g);
    moe_gemm<<<dim3(2048), dim3(640), 0, stream>>>(xb, Wt, g, bsh, bsp, out);
}

// Round 14
// 410.999 us; speedup vs baseline: 1.3680x; 1.3680x over previous
//
#include <hip/hip_runtime.h>
#include <stdint.h>

// Problem constants
#define kB  16384
#define kD  1024
#define kDE 512

typedef __bf16 bf16x8 __attribute__((ext_vector_type(8)));
typedef float  f32x4  __attribute__((ext_vector_type(4)));

__device__ __forceinline__ unsigned short f2bf(float f) {
    union { float f; unsigned u; } v; v.f = f;
    unsigned r = v.u + 0x7FFFu + ((v.u >> 16) & 1u);   // round-to-nearest-even
    return (unsigned short)(r >> 16);
}

__device__ __forceinline__ void async16(unsigned short* lds, const unsigned short* g) {
    __builtin_amdgcn_global_load_lds(
        (const __attribute__((address_space(1))) unsigned int*)g,
        (__attribute__((address_space(3))) unsigned int*)lds, 16, 0, 0);
}

// ---------------- prep: transpose + convert weights to bf16 ----------------
__global__ __launch_bounds__(256) void prep_w(const float* __restrict__ Wsh,
                                              const float* __restrict__ Wsp,
                                              unsigned short* __restrict__ Wt) {
    __shared__ float tile[64][65];
    const int slot = blockIdx.z;
    const int k0 = blockIdx.x * 64;
    const int n0 = blockIdx.y * 64;
    const float* src = (slot < 4) ? (Wsh + (size_t)slot * kD * kDE)
                                  : (Wsp + (size_t)(slot - 4) * kD * kDE);
    const int tid = threadIdx.x;
    const int lr = tid >> 4, lc = (tid & 15) * 4;
#pragma unroll
    for (int i = 0; i < 4; i++) {
        const float4 v = *(const float4*)&src[(size_t)(k0 + lr + i * 16) * kDE + n0 + lc];
        tile[lr + i * 16][lc + 0] = v.x;
        tile[lr + i * 16][lc + 1] = v.y;
        tile[lr + i * 16][lc + 2] = v.z;
        tile[lr + i * 16][lc + 3] = v.w;
    }
    __syncthreads();
    const int wn = tid >> 2, wk = (tid & 3) * 16;
    unsigned short* dst = Wt + (size_t)slot * kDE * kD + (size_t)(n0 + wn) * kD + k0 + wk;
#pragma unroll
    for (int j = 0; j < 4; j++) {
        ushort4 h;
        h.x = f2bf(tile[wk + j * 4 + 0][wn]);
        h.y = f2bf(tile[wk + j * 4 + 1][wn]);
        h.z = f2bf(tile[wk + j * 4 + 2][wn]);
        h.w = f2bf(tile[wk + j * 4 + 3][wn]);
        *(ushort4*)(dst + j * 4) = h;
    }
}

// ------------- fused x fp32->bf16 conversion + gate softmax ---------------
__global__ __launch_bounds__(256) void conv_gate(
    const float* __restrict__ x0, const float* __restrict__ x1,
    const float* __restrict__ Wg, const float* __restrict__ bg,
    unsigned short* __restrict__ xb, float* __restrict__ g) {
    const int wid = threadIdx.x >> 6, lane = threadIdx.x & 63;
    const int r = blockIdx.x * 4 + wid;
    const int t = r >> 14, b = r & 16383;
    const float* xrow = (t ? x1 : x0) + (size_t)b * kD;
    unsigned short* xbrow = xb + (size_t)(t * kB + b) * kD;
    const float* Wgt = Wg + t * kD * 8;
    float p[8] = {0.f,0.f,0.f,0.f,0.f,0.f,0.f,0.f};
#pragma unroll
    for (int it = 0; it < 4; it++) {
        const int d0 = it * 256 + lane * 4;
        const float4 v = *(const float4*)(xrow + d0);
        ushort4 h;
        h.x = f2bf(v.x); h.y = f2bf(v.y); h.z = f2bf(v.z); h.w = f2bf(v.w);
        *(ushort4*)(xbrow + d0) = h;
        const float xv[4] = {v.x, v.y, v.z, v.w};
#pragma unroll
        for (int j = 0; j < 4; j++) {
            const float* wrow = Wgt + (size_t)(d0 + j) * 8;
            const float4 wa = *(const float4*)wrow;
            const float4 wb = *(const float4*)(wrow + 4);
            p[0] += xv[j] * wa.x; p[1] += xv[j] * wa.y;
            p[2] += xv[j] * wa.z; p[3] += xv[j] * wa.w;
            p[4] += xv[j] * wb.x; p[5] += xv[j] * wb.y;
            p[6] += xv[j] * wb.z; p[7] += xv[j] * wb.w;
        }
    }
#pragma unroll
    for (int e = 0; e < 8; e++) {
        float v = p[e];
#pragma unroll
        for (int s = 1; s < 64; s <<= 1) v += __shfl_xor(v, s, 64);
        p[e] = v;
    }
    float lg[8];
#pragma unroll
    for (int e = 0; e < 8; e++) lg[e] = p[e] + bg[t * 8 + e];
    float mx = lg[0];
#pragma unroll
    for (int e = 1; e < 8; e++) mx = fmaxf(mx, lg[e]);
    float s = 0.f;
#pragma unroll
    for (int e = 0; e < 8; e++) { lg[e] = __expf(lg[e] - mx); s += lg[e]; }
    const float inv = 1.f / s;
    if (lane == 0) {
        float* gp = g + (size_t)(t * kB + b) * 8;
        float4 g0 = {lg[0]*inv, lg[1]*inv, lg[2]*inv, lg[3]*inv};
        float4 g1 = {lg[4]*inv, lg[5]*inv, lg[6]*inv, lg[7]*inv};
        *(float4*)gp = g0;
        *(float4*)(gp + 4) = g1;
    }
}

// --------------------------- fused MoE GEMM (R6 lock-in) -------------------
// Experts inner: M=128 x (8 experts x 64 cols); 8 waves (2Mx4N); BK=64.
// Double-buffered LDS; counted vmcnt(10); K-loop unrolled x2 (compile-time
// LDS buffer indices). Best measured: 305.3 us, MfmaUtil 40%, conflicts 0.
__global__ __launch_bounds__(512, 2) void moe_gemm(
    const unsigned short* __restrict__ xb, const unsigned short* __restrict__ Wt,
    const float* __restrict__ g, const float* __restrict__ bsh,
    const float* __restrict__ bsp, float* __restrict__ out) {
    __shared__ __align__(16) unsigned short As[2][128 * 64];      // 32 KB
    __shared__ __align__(16) unsigned short Bs[2][8 * 64 * 64];   // 128 KB

    // XCD-bijective swizzle (nwg=2048, %8==0)
    const int bid = blockIdx.x;
    const int swz = (bid & 7) * 256 + (bid >> 3);
    const int ct = swz & 7;
    const int rt = (swz >> 3) & 127;
    const int t  = swz >> 10;
    const int n0 = ct * 64;

    const int tid = threadIdx.x, wid = tid >> 6, lane = tid & 63;
    const int wr = wid >> 2, wc = wid & 3;

    // staging (pre-swizzled global source, linear LDS dest — rule #21)
    const int swzChunk = ((lane & 7) ^ ((lane >> 3) & 7)) * 8;
    const unsigned short* aSrc = xb + (size_t)t * kB * kD +
        (size_t)(rt * 128 + wid * 16 + (lane >> 3)) * kD + swzChunk;
    const int slot = (wid < 4) ? wid : (4 + t * 4 + (wid - 4));
    const unsigned short* bSrc = Wt + (size_t)slot * kDE * kD +
        (size_t)(n0 + (lane >> 3)) * kD + swzChunk;

    // fragment read offsets
    const int rAbase = (wr * 64 + (lane & 15)) * 64;
    const int bOff   = (wc * 16 + (lane & 15)) * 64;
    const int lx     = lane & 7;
    const int kg     = lane >> 4;

    f32x4 acc[8][4];
#pragma unroll
    for (int e = 0; e < 8; e++)
#pragma unroll
        for (int m = 0; m < 4; m++) acc[e][m] = (f32x4){0.f, 0.f, 0.f, 0.f};

#define STAGE(buf, kt)                                                        \
    {                                                                         \
        const int k0_ = (kt) * 64;                                            \
        _Pragma("unroll")                                                     \
        for (int i = 0; i < 2; i++)                                           \
            async16(&As[buf][wid * 1024 + i * 512], aSrc + k0_ + i * 8 * kD); \
        _Pragma("unroll")                                                     \
        for (int j = 0; j < 8; j++)                                           \
            async16(&Bs[buf][wid * 4096 + j * 512], bSrc + k0_ + j * 8 * kD); \
    }

#define COMPUTE(buf)                                                          \
    {                                                                         \
        _Pragma("unroll")                                                     \
        for (int ks = 0; ks < 2; ks++) {                                      \
            const int p8 = ((ks * 4 + kg) ^ lx) * 8;                          \
            bf16x8 af[4];                                                     \
            _Pragma("unroll")                                                 \
            for (int m = 0; m < 4; m++)                                       \
                af[m] = *(const bf16x8*)&As[buf][rAbase + m * 1024 + p8];     \
            _Pragma("unroll")                                                 \
            for (int e = 0; e < 8; e++) {                                     \
                bf16x8 bf = *(const bf16x8*)&Bs[buf][e * 4096 + bOff + p8];   \
                _Pragma("unroll")                                             \
                for (int m = 0; m < 4; m++)                                   \
                    acc[e][m] = __builtin_amdgcn_mfma_f32_16x16x32_bf16(      \
                        af[m], bf, acc[e][m], 0, 0, 0);                       \
            }                                                                 \
        }                                                                     \
    }

    STAGE(0, 0);                                   // 10 loads in flight
    for (int kt2 = 0; kt2 < 8; ++kt2) {
        STAGE(1, kt2 * 2 + 1);
        asm volatile("s_waitcnt vmcnt(10)" ::: "memory");
        __builtin_amdgcn_s_barrier();
        COMPUTE(0);
        __builtin_amdgcn_s_barrier();
        STAGE(0, (kt2 * 2 + 2) & 15);              // last iter restages t0 (benign)
        asm volatile("s_waitcnt vmcnt(10)" ::: "memory");
        __builtin_amdgcn_s_barrier();
        COMPUTE(1);
        __builtin_amdgcn_s_barrier();
    }
    asm volatile("s_waitcnt vmcnt(0)" ::: "memory");

#undef STAGE
#undef COMPUTE

    // ---- epilogue: out = sum_e g_e * relu(acc[e] + bias_e), bias direct ----
    const int col = n0 + wc * 16 + (lane & 15);
    float bv[8];
#pragma unroll
    for (int e = 0; e < 8; e++)
        bv[e] = (e < 4) ? bsh[e * kDE + col] : bsp[(t * 4 + (e - 4)) * kDE + col];

#pragma unroll
    for (int m = 0; m < 4; m++) {
        const int r0 = rt * 128 + wr * 64 + m * 16 + kg * 4;
#pragma unroll
        for (int q = 0; q < 4; q++) {
            const float* gp = g + ((size_t)t * kB + r0 + q) * 8;
            const float4 ga = *(const float4*)gp;
            const float4 gb = *(const float4*)(gp + 4);
            float s = ga.x * fmaxf(acc[0][m][q] + bv[0], 0.f)
                    + ga.y * fmaxf(acc[1][m][q] + bv[1], 0.f)
                    + ga.z * fmaxf(acc[2][m][q] + bv[2], 0.f)
                    + ga.w * fmaxf(acc[3][m][q] + bv[3], 0.f)
                    + gb.x * fmaxf(acc[4][m][q] + bv[4], 0.f)
                    + gb.y * fmaxf(acc[5][m][q] + bv[5], 0.f)
                    + gb.z * fmaxf(acc[6][m][q] + bv[6], 0.f)
                    + gb.w * fmaxf(acc[7][m][q] + bv[7], 0.f);
            out[((size_t)(r0 + q) * 2 + t) * kDE + col] = s;
        }
    }
}

extern "C" void kernel_launch(void* const* d_in, const int* in_sizes, int n_in,
                              void* d_out, int out_size, void* d_ws, size_t ws_size,
                              hipStream_t stream) {
    const float* x0  = (const float*)d_in[0];
    const float* x1  = (const float*)d_in[1];
    const float* Wsh = (const float*)d_in[2];
    const float* bsh = (const float*)d_in[3];
    const float* Wsp = (const float*)d_in[4];
    const float* bsp = (const float*)d_in[5];
    const float* Wg  = (const float*)d_in[6];
    const float* bg  = (const float*)d_in[7];
    float* out = (float*)d_out;

    // ws layout (bytes): xb 67108864 | Wt 12582912 | g 1048576
    char* ws = (char*)d_ws;
    unsigned short* xb = (unsigned short*)ws;
    unsigned short* Wt = (unsigned short*)(ws + 67108864);
    float* g  = (float*)(ws + 67108864 + 12582912);

    prep_w<<<dim3(16, 8, 12), dim3(256), 0, stream>>>(Wsh, Wsp, Wt);
    conv_gate<<<dim3(8192), dim3(256), 0, stream>>>(x0, x1, Wg, bg, xb, g);
    moe_gemm<<<dim3(2048), dim3(512), 0, stream>>>(xb, Wt, g, bsh, bsp, out);
}